// Round 3
// baseline (796.865 us; speedup 1.0000x reference)
//
#include <hip/hip_runtime.h>
#include <hip/hip_bf16.h>

typedef __hip_bfloat16 bf16;

#define D 128
#define H 8
#define EDIM 16
#define SQRT_D 11.313708498984761f

__device__ __forceinline__ float cvt(float v) { return v; }
__device__ __forceinline__ float cvt(bf16 v) { return __bfloat162float(v); }

// ------------------------------------------------------- input dtype detect
// bf16 data (|v|<~1): exponent field small. fp32 viewed as u16 halves: even
// halves ~uniform -> ~48% exponents in (132,255). flag=1 -> inputs are fp32.
__global__ void k_detect(const unsigned short* __restrict__ u, int* flag) {
    __shared__ int sh[256];
    int t = threadIdx.x;
    int cnt = 0;
    for (int i = t; i < 4096; i += 256) {
        int e = (u[i] >> 7) & 0xFF;
        cnt += (e > 132 && e < 255) ? 1 : 0;
    }
    sh[t] = cnt;
    __syncthreads();
    for (int s = 128; s > 0; s >>= 1) {
        if (t < s) sh[t] += sh[t + s];
        __syncthreads();
    }
    if (t == 0) *flag = (sh[0] > 100) ? 1 : 0;
}

// ---------------------------------------------------------------- zero fill
__global__ void k_zero(int* p, int count) {
    int i = blockIdx.x * blockDim.x + threadIdx.x;
    if (i < count) p[i] = 0;
}

// ------------------------------------------------------------ CSR: histogram
__global__ void k_hist(const int* __restrict__ ei, int* __restrict__ deg, int nE) {
    int e = blockIdx.x * blockDim.x + threadIdx.x;
    if (e < nE) atomicAdd(&deg[ei[nE + e]], 1);
}

// ---------------------------------------------- CSR: single-block scan (n<=~500k)
__global__ __launch_bounds__(1024) void k_scan(
    const int* __restrict__ deg, int* __restrict__ row_ptr,
    int* __restrict__ cursor, int n)
{
    __shared__ int part[1024];
    const int t = threadIdx.x;
    const int chunk = (n + 1023) >> 10;
    const int beg = t * chunk;
    const int end = min(beg + chunk, n);
    int s = 0;
    for (int i = beg; i < end; ++i) s += deg[i];
    part[t] = s;
    __syncthreads();
    for (int off = 1; off < 1024; off <<= 1) {
        int v = (t >= off) ? part[t - off] : 0;
        __syncthreads();
        part[t] += v;
        __syncthreads();
    }
    int run = (t > 0) ? part[t - 1] : 0;
    for (int i = beg; i < end; ++i) {
        row_ptr[i] = run;
        cursor[i] = run;
        run += deg[i];
    }
    if (t == 1023) row_ptr[n] = part[1023];
}

// ------------------------------------------------------------ CSR: scatter
__global__ void k_scatter(const int* __restrict__ ei, int* __restrict__ cursor,
                          int2* __restrict__ csr, int nE)
{
    int e = blockIdx.x * blockDim.x + threadIdx.x;
    if (e < nE) {
        int src = ei[e], dst = ei[nE + e];
        int pos = atomicAdd(&cursor[dst], 1);
        csr[pos] = make_int2(src, e);
    }
}

// ------------------------------------------------- node transform: xl / xr
template <typename T>
__device__ __forceinline__ void node_body(
    const int* __restrict__ x, const T* __restrict__ emb,
    const T* __restrict__ Wl, const T* __restrict__ bl,
    const T* __restrict__ Wr, const T* __restrict__ br,
    float* __restrict__ xl, float* __restrict__ xr, int n)
{
    __shared__ float hS[8][D];
    const int t = threadIdx.x;
    const int d = t & (D - 1);
    const int r = t >> 7;
    const int nb = blockIdx.x * 8;

    #pragma unroll
    for (int j = 0; j < 4; ++j) {
        int row = r + 2 * j;
        int node = nb + row;
        float hv = 0.0f;
        if (node < n) {
            int tok = x[node];
            hv = cvt(emb[(size_t)tok * D + d]) * SQRT_D;
        }
        hS[row][d] = hv;
    }
    __syncthreads();

    float accl[4], accr[4];
    const float blv = cvt(bl[d]);
    const float brv = cvt(br[d]);
    #pragma unroll
    for (int j = 0; j < 4; ++j) { accl[j] = blv; accr[j] = brv; }

    for (int k = 0; k < D; ++k) {
        float wl = cvt(Wl[k * D + d]);
        float wr = cvt(Wr[k * D + d]);
        #pragma unroll
        for (int j = 0; j < 4; ++j) {
            float hv = hS[r + 2 * j][k];
            accl[j] += hv * wl;
            accr[j] += hv * wr;
        }
    }

    #pragma unroll
    for (int j = 0; j < 4; ++j) {
        int node = nb + r + 2 * j;
        if (node < n) {
            xl[(size_t)node * D + d] = accl[j];
            xr[(size_t)node * D + d] = accr[j];
        }
    }
}

__global__ __launch_bounds__(256) void k_node(
    const int* x, const void* emb, const void* Wl, const void* bl,
    const void* Wr, const void* br, float* xl, float* xr, int n,
    const int* flag)
{
    if (*flag)
        node_body<float>(x, (const float*)emb, (const float*)Wl, (const float*)bl,
                         (const float*)Wr, (const float*)br, xl, xr, n);
    else
        node_body<bf16>(x, (const bf16*)emb, (const bf16*)Wl, (const bf16*)bl,
                        (const bf16*)Wr, (const bf16*)br, xl, xr, n);
}

// -------------------------------------- node-centric aggregation (no atomics)
// block = 256 = 2 slots x 128 lanes; one dst node per slot per iteration.
// lane: d = t&127 (d = h*16+c), head group = 16 consecutive lanes in one wave.
// Unnormalized softmax: acc[d] = sum_e exp(score_eh) * xl[src,d]; den = sum ex.
// Also fuses +bias and BN partial-sum accumulation.
template <typename T>
__device__ __forceinline__ void agg_body(
    const int* __restrict__ row_ptr, const int2* __restrict__ csr,
    const T* __restrict__ ew, const T* __restrict__ We,
    const T* __restrict__ att, const T* __restrict__ bias,
    const float* __restrict__ xl, const float* __restrict__ xr,
    float* __restrict__ vpre, float* __restrict__ bnsum,
    float* __restrict__ bnsumsq, int n)
{
    const int t = threadIdx.x;
    const int d = t & (D - 1);
    const int slot = t >> 7;
    const int k15 = t & 15;

    float we[EDIM];
    #pragma unroll
    for (int k = 0; k < EDIM; ++k) we[k] = cvt(We[k * D + d]);
    const float attd = cvt(att[d]);
    const float biasd = cvt(bias[d]);

    float s = 0.0f, s2 = 0.0f;
    for (int i = blockIdx.x * 2 + slot; i < n; i += gridDim.x * 2) {
        const int beg = row_ptr[i];
        const int end = row_ptr[i + 1];
        const float xrd = xr[(size_t)i * D + d];
        float acc = 0.0f, den = 0.0f;
        for (int j = beg; j < end; ++j) {
            int2 se = csr[j];
            float ewk = cvt(ew[(size_t)se.y * EDIM + k15]);
            float eemb = 0.0f;
            #pragma unroll
            for (int k = 0; k < EDIM; ++k)
                eemb += __shfl(ewk, k, 16) * we[k];
            float xls = xl[(size_t)se.x * D + d];
            float z = xls + xrd + eemb;
            float m = z > 0.0f ? z : 0.2f * z;     // leaky_relu slope 0.2
            float p = m * attd;
            p += __shfl_xor(p, 8, 16);
            p += __shfl_xor(p, 4, 16);
            p += __shfl_xor(p, 2, 16);
            p += __shfl_xor(p, 1, 16);
            float ex = __expf(p);
            den += ex;
            acc += ex * xls;
        }
        float v = (den > 0.0f ? acc / den : 0.0f) + biasd;
        vpre[(size_t)i * D + d] = v;
        s += v;
        s2 += v * v;
    }

    __shared__ float sS[2][D], s2S[2][D];
    sS[slot][d] = s;
    s2S[slot][d] = s2;
    __syncthreads();
    if (slot == 0) {
        atomicAdd(&bnsum[d], sS[0][d] + sS[1][d]);
        atomicAdd(&bnsumsq[d], s2S[0][d] + s2S[1][d]);
    }
}

__global__ __launch_bounds__(256) void k_agg(
    const int* row_ptr, const int2* csr, const void* ew, const void* We,
    const void* att, const void* bias, const float* xl, const float* xr,
    float* vpre, float* bnsum, float* bnsumsq, int n, const int* flag)
{
    if (*flag)
        agg_body<float>(row_ptr, csr, (const float*)ew, (const float*)We,
                        (const float*)att, (const float*)bias, xl, xr,
                        vpre, bnsum, bnsumsq, n);
    else
        agg_body<bf16>(row_ptr, csr, (const bf16*)ew, (const bf16*)We,
                       (const bf16*)att, (const bf16*)bias, xl, xr,
                       vpre, bnsum, bnsumsq, n);
}

// ------------------------------------------------------------- finalize
template <typename T>
__device__ __forceinline__ void final_body(
    const float* __restrict__ vpre, const T* __restrict__ gamma,
    const T* __restrict__ beta, const float* __restrict__ bnsum,
    const float* __restrict__ bnsumsq, float* __restrict__ out, int n)
{
    int idx = blockIdx.x * blockDim.x + threadIdx.x;
    if (idx >= n * D) return;
    int d = idx & (D - 1);
    float v = vpre[idx];
    float invN = 1.0f / (float)n;
    float mean = bnsum[d] * invN;
    float var = bnsumsq[d] * invN - mean * mean;
    float y = (v - mean) * rsqrtf(var + 1e-5f) * cvt(gamma[d]) + cvt(beta[d]);
    y = y > 0.0f ? y : 0.01f * y;   // leaky_relu slope 0.01
    out[idx] = y;                   // output is fp32
}

__global__ __launch_bounds__(256) void k_final(
    const float* vpre, const void* gamma, const void* beta,
    const float* bnsum, const float* bnsumsq, float* out, int n,
    const int* flag)
{
    if (*flag)
        final_body<float>(vpre, (const float*)gamma, (const float*)beta,
                          bnsum, bnsumsq, out, n);
    else
        final_body<bf16>(vpre, (const bf16*)gamma, (const bf16*)beta,
                         bnsum, bnsumsq, out, n);
}

// ---------------------------------------------------------------- launch
extern "C" void kernel_launch(void* const* d_in, const int* in_sizes, int n_in,
                              void* d_out, int out_size, void* d_ws, size_t ws_size,
                              hipStream_t stream)
{
    const int*  x     = (const int*)d_in[0];
    const int*  ei    = (const int*)d_in[1];
    const void* ew    = d_in[2];
    const void* emb   = d_in[3];
    const void* Wl    = d_in[4];
    const void* bl    = d_in[5];
    const void* Wr    = d_in[6];
    const void* br    = d_in[7];
    const void* att   = d_in[8];
    const void* We    = d_in[9];
    const void* bias  = d_in[10];
    const void* gamma = d_in[11];
    const void* beta  = d_in[12];

    const int n  = in_sizes[0];        // 50000
    const int nE = in_sizes[1] / 2;    // 800000

    // ws layout: xl | xr | vpre | deg | bnsum | bnsumsq | flag | row_ptr | cursor | csr
    float* ws      = (float*)d_ws;
    float* xl      = ws;
    float* xr      = xl + (size_t)n * D;
    float* vpre    = xr + (size_t)n * D;
    int*   deg     = (int*)(vpre + (size_t)n * D);
    float* bnsum   = (float*)(deg + n);
    float* bnsumsq = bnsum + D;
    int*   flag    = (int*)(bnsumsq + D);
    int*   row_ptr = flag + 1;
    int*   cursor  = row_ptr + (n + 1);
    uintptr_t p    = (uintptr_t)(cursor + n);
    p = (p + 7) & ~(uintptr_t)7;
    int2*  csr     = (int2*)p;

    // zero deg + bnsum + bnsumsq (contiguous ints/floats)
    int zcount = n + 2 * D;
    k_zero<<<(zcount + 255) / 256, 256, 0, stream>>>(deg, zcount);

    k_detect<<<1, 256, 0, stream>>>((const unsigned short*)emb, flag);

    k_hist<<<(nE + 255) / 256, 256, 0, stream>>>(ei, deg, nE);
    k_scan<<<1, 1024, 0, stream>>>(deg, row_ptr, cursor, n);
    k_scatter<<<(nE + 255) / 256, 256, 0, stream>>>(ei, cursor, csr, nE);

    k_node<<<(n + 7) / 8, 256, 0, stream>>>(x, emb, Wl, bl, Wr, br, xl, xr, n, flag);

    k_agg<<<2500, 256, 0, stream>>>(row_ptr, csr, ew, We, att, bias,
                                    xl, xr, vpre, bnsum, bnsumsq, n, flag);

    int totalOut = n * D;
    k_final<<<(totalOut + 255) / 256, 256, 0, stream>>>(vpre, gamma, beta,
                                                        bnsum, bnsumsq,
                                                        (float*)d_out, n, flag);
}

// Round 4
// 675.979 us; speedup vs baseline: 1.1788x; 1.1788x over previous
//
#include <hip/hip_runtime.h>
#include <hip/hip_bf16.h>

typedef __hip_bfloat16 bf16;

#define D 128
#define H 8
#define EDIM 16
#define SQRT_D 11.313708498984761f

__device__ __forceinline__ float cvt(float v) { return v; }
__device__ __forceinline__ float cvt(bf16 v) { return __bfloat162float(v); }

// interleaved channel position: channel d -> (d&63)*2 + (d>>6)
__device__ __forceinline__ int ilv(int d) { return ((d & 63) << 1) | (d >> 6); }

// --------------------------------------- zero fill + dtype detect (block 0)
// flag=1 -> float inputs are fp32; flag=0 -> bf16.
__global__ void k_zero_detect(int* p, int count,
                              const unsigned short* __restrict__ u, int* flag)
{
    int i = blockIdx.x * blockDim.x + threadIdx.x;
    if (i < count) p[i] = 0;
    if (blockIdx.x == 0) {
        __shared__ int sh[256];
        int t = threadIdx.x;
        int cnt = 0;
        for (int k = t; k < 4096; k += 256) {
            int e = (u[k] >> 7) & 0xFF;
            cnt += (e > 132 && e < 255) ? 1 : 0;
        }
        sh[t] = cnt;
        __syncthreads();
        for (int s = 128; s > 0; s >>= 1) {
            if (t < s) sh[t] += sh[t + s];
            __syncthreads();
        }
        if (t == 0) *flag = (sh[0] > 100) ? 1 : 0;
    }
}

// ---------------------------------------------- CSR scan (single block)
__global__ __launch_bounds__(1024) void k_scan(
    const int* __restrict__ deg, int* __restrict__ row_ptr,
    int* __restrict__ cursor, int n)
{
    __shared__ int part[1024];
    const int t = threadIdx.x;
    const int chunk = (n + 1023) >> 10;
    const int beg = t * chunk;
    const int end = min(beg + chunk, n);
    int s = 0;
    for (int i = beg; i < end; ++i) s += deg[i];
    part[t] = s;
    __syncthreads();
    for (int off = 1; off < 1024; off <<= 1) {
        int v = (t >= off) ? part[t - off] : 0;
        __syncthreads();
        part[t] += v;
        __syncthreads();
    }
    int run = (t > 0) ? part[t - 1] : 0;
    for (int i = beg; i < end; ++i) {
        row_ptr[i] = run;
        cursor[i] = run;
        run += deg[i];
    }
    if (t == 1023) row_ptr[n] = part[1023];
}

// ------------------------------------------------------------ CSR scatter
__global__ void k_scatter(const int* __restrict__ ei, int* __restrict__ cursor,
                          int2* __restrict__ csr, int nE)
{
    int e = blockIdx.x * blockDim.x + threadIdx.x;
    if (e < nE) {
        int src = ei[e], dst = ei[nE + e];
        int pos = atomicAdd(&cursor[dst], 1);
        csr[pos] = make_int2(src, e);
    }
}

// ----------------------------- fused: node transform (xl/xr) + dst histogram
template <typename T>
__device__ __forceinline__ void node_body(
    const int* __restrict__ x, const T* __restrict__ emb,
    const T* __restrict__ Wl, const T* __restrict__ bl,
    const T* __restrict__ Wr, const T* __restrict__ br,
    float* __restrict__ xl, float* __restrict__ xr, int n, int nb)
{
    __shared__ float hS[8][D];
    const int t = threadIdx.x;
    const int d = t & (D - 1);
    const int r = t >> 7;

    #pragma unroll
    for (int j = 0; j < 4; ++j) {
        int row = r + 2 * j;
        int node = nb + row;
        float hv = 0.0f;
        if (node < n) {
            int tok = x[node];
            hv = cvt(emb[(size_t)tok * D + d]) * SQRT_D;
        }
        hS[row][d] = hv;
    }
    __syncthreads();

    float accl[4], accr[4];
    const float blv = cvt(bl[d]);
    const float brv = cvt(br[d]);
    #pragma unroll
    for (int j = 0; j < 4; ++j) { accl[j] = blv; accr[j] = brv; }

    for (int k = 0; k < D; ++k) {
        float wl = cvt(Wl[k * D + d]);
        float wr = cvt(Wr[k * D + d]);
        #pragma unroll
        for (int j = 0; j < 4; ++j) {
            float hv = hS[r + 2 * j][k];
            accl[j] += hv * wl;
            accr[j] += hv * wr;
        }
    }

    const int id = ilv(d);
    #pragma unroll
    for (int j = 0; j < 4; ++j) {
        int node = nb + r + 2 * j;
        if (node < n) {
            xl[(size_t)node * D + id] = accl[j];
            xr[(size_t)node * D + id] = accr[j];
        }
    }
}

__global__ __launch_bounds__(256) void k_node_hist(
    const int* x, const void* emb, const void* Wl, const void* bl,
    const void* Wr, const void* br, float* xl, float* xr, int n,
    const int* flag, const int* ei, int* deg, int nE, int nodeBlocks)
{
    if ((int)blockIdx.x < nodeBlocks) {
        int nb = blockIdx.x * 8;
        if (*flag)
            node_body<float>(x, (const float*)emb, (const float*)Wl, (const float*)bl,
                             (const float*)Wr, (const float*)br, xl, xr, n, nb);
        else
            node_body<bf16>(x, (const bf16*)emb, (const bf16*)Wl, (const bf16*)bl,
                            (const bf16*)Wr, (const bf16*)br, xl, xr, n, nb);
    } else {
        int e = (blockIdx.x - nodeBlocks) * 256 + threadIdx.x;
        if (e < nE) atomicAdd(&deg[ei[nE + e]], 1);
    }
}

// ------------------------------------------------ per-edge W_e row registers
template <typename T> struct EwReg;
template <> struct EwReg<bf16> {
    unsigned v[8];
    __device__ __forceinline__ void load(const bf16* p, int e) {
        const uint4* q = (const uint4*)(p + (size_t)e * EDIM);
        uint4 A = q[0], B = q[1];
        v[0] = A.x; v[1] = A.y; v[2] = A.z; v[3] = A.w;
        v[4] = B.x; v[5] = B.y; v[6] = B.z; v[7] = B.w;
    }
    __device__ __forceinline__ float2 pair(int q) const {   // {ew[2q], ew[2q+1]}
        return make_float2(__uint_as_float(v[q] << 16),
                           __uint_as_float(v[q] & 0xffff0000u));
    }
};
template <> struct EwReg<float> {
    float v[16];
    __device__ __forceinline__ void load(const float* p, int e) {
        const float4* q = (const float4*)(p + (size_t)e * EDIM);
        float4 A = q[0], B = q[1], Cc = q[2], Dd = q[3];
        v[0]=A.x; v[1]=A.y; v[2]=A.z; v[3]=A.w;
        v[4]=B.x; v[5]=B.y; v[6]=B.z; v[7]=B.w;
        v[8]=Cc.x; v[9]=Cc.y; v[10]=Cc.z; v[11]=Cc.w;
        v[12]=Dd.x; v[13]=Dd.y; v[14]=Dd.z; v[15]=Dd.w;
    }
    __device__ __forceinline__ float2 pair(int q) const {
        return make_float2(v[2 * q], v[2 * q + 1]);
    }
};

// ------------------------------- node-centric aggregation, 1 wave = 1 node
// lane l owns channels d0=l, d1=l+64 (interleaved xl/xr layout -> float2).
// Unnormalized softmax; fuses +bias and BN partial sums.
template <typename T>
__device__ __forceinline__ void agg_body(
    const int* __restrict__ row_ptr, const int2* __restrict__ csr,
    const T* __restrict__ ew, const T* __restrict__ We,
    const T* __restrict__ att, const T* __restrict__ bias,
    const float* __restrict__ xl, const float* __restrict__ xr,
    float* __restrict__ vpre, float* __restrict__ bnsum,
    float* __restrict__ bnsumsq, int n)
{
    const int t = threadIdx.x;
    const int l = t & 63;
    const int slot = t >> 6;          // 4 waves per block
    const int d0 = l, d1 = l + 64;

    float we0[EDIM], we1[EDIM];
    #pragma unroll
    for (int k = 0; k < EDIM; ++k) {
        we0[k] = cvt(We[k * D + d0]);
        we1[k] = cvt(We[k * D + d1]);
    }
    const float att0 = cvt(att[d0]), att1 = cvt(att[d1]);
    const float b0 = cvt(bias[d0]), b1 = cvt(bias[d1]);

    float s0 = 0, s20 = 0, s1 = 0, s21 = 0;
    const int nslots = gridDim.x * 4;
    for (int i = blockIdx.x * 4 + slot; i < n; i += nslots) {
        const int beg = row_ptr[i];
        const int end = row_ptr[i + 1];
        const float2 xrv = *(const float2*)(xr + (size_t)i * D + 2 * l);
        float acc0 = 0, acc1 = 0, den0 = 0, den1 = 0;

        int2 se; EwReg<T> w; float2 xv;
        if (beg < end) {
            se = csr[beg];
            w.load(ew, se.y);
            xv = *(const float2*)(xl + (size_t)se.x * D + 2 * l);
        }
        for (int j = beg; j < end; ++j) {
            EwReg<T> wc = w;
            float2 xc = xv;
            if (j + 1 < end) {                 // prefetch next edge
                se = csr[j + 1];
                w.load(ew, se.y);
                xv = *(const float2*)(xl + (size_t)se.x * D + 2 * l);
            }
            float e0 = 0.0f, e1 = 0.0f;
            #pragma unroll
            for (int q = 0; q < 8; ++q) {
                float2 pr = wc.pair(q);
                e0 = fmaf(pr.y, we0[2 * q + 1], fmaf(pr.x, we0[2 * q], e0));
                e1 = fmaf(pr.y, we1[2 * q + 1], fmaf(pr.x, we1[2 * q], e1));
            }
            float z0 = xc.x + xrv.x + e0;
            float z1 = xc.y + xrv.y + e1;
            float m0 = z0 > 0.0f ? z0 : 0.2f * z0;   // leaky_relu 0.2
            float m1 = z1 > 0.0f ? z1 : 0.2f * z1;
            float p0 = m0 * att0, p1 = m1 * att1;
            #pragma unroll
            for (int o = 8; o; o >>= 1) {            // reduce over 16-lane head
                p0 += __shfl_xor(p0, o, 16);
                p1 += __shfl_xor(p1, o, 16);
            }
            float ex0 = __expf(p0), ex1 = __expf(p1);
            den0 += ex0; den1 += ex1;
            acc0 = fmaf(ex0, xc.x, acc0);
            acc1 = fmaf(ex1, xc.y, acc1);
        }
        float v0 = (den0 > 0.0f ? acc0 / den0 : 0.0f) + b0;
        float v1 = (den1 > 0.0f ? acc1 / den1 : 0.0f) + b1;
        float* vp = vpre + (size_t)i * D + 2 * l;
        vp[0] = v0; vp[1] = v1;
        s0 += v0; s20 += v0 * v0;
        s1 += v1; s21 += v1 * v1;
    }

    __shared__ float sh[4][2][64], sh2[4][2][64];
    sh[slot][0][l] = s0;  sh[slot][1][l] = s1;
    sh2[slot][0][l] = s20; sh2[slot][1][l] = s21;
    __syncthreads();
    if (t < 128) {
        int s_ = t >> 6, l2 = t & 63;
        int d = l2 + 64 * s_;
        float a = 0, a2 = 0;
        #pragma unroll
        for (int q = 0; q < 4; ++q) { a += sh[q][s_][l2]; a2 += sh2[q][s_][l2]; }
        atomicAdd(&bnsum[d], a);
        atomicAdd(&bnsumsq[d], a2);
    }
}

__global__ __launch_bounds__(256) void k_agg(
    const int* row_ptr, const int2* csr, const void* ew, const void* We,
    const void* att, const void* bias, const float* xl, const float* xr,
    float* vpre, float* bnsum, float* bnsumsq, int n, const int* flag)
{
    if (*flag)
        agg_body<float>(row_ptr, csr, (const float*)ew, (const float*)We,
                        (const float*)att, (const float*)bias, xl, xr,
                        vpre, bnsum, bnsumsq, n);
    else
        agg_body<bf16>(row_ptr, csr, (const bf16*)ew, (const bf16*)We,
                       (const bf16*)att, (const bf16*)bias, xl, xr,
                       vpre, bnsum, bnsumsq, n);
}

// ------------------------------------------------------------- finalize
template <typename T>
__device__ __forceinline__ void final_body(
    const float* __restrict__ vpre, const T* __restrict__ gamma,
    const T* __restrict__ beta, const float* __restrict__ bnsum,
    const float* __restrict__ bnsumsq, float* __restrict__ out, int n)
{
    int idx = blockIdx.x * blockDim.x + threadIdx.x;
    if (idx >= n * D) return;
    int p = idx & (D - 1);
    int d = (p >> 1) + ((p & 1) << 6);   // undo interleave
    float v = vpre[idx];
    float invN = 1.0f / (float)n;
    float mean = bnsum[d] * invN;
    float var = bnsumsq[d] * invN - mean * mean;
    float y = (v - mean) * rsqrtf(var + 1e-5f) * cvt(gamma[d]) + cvt(beta[d]);
    y = y > 0.0f ? y : 0.01f * y;        // leaky_relu 0.01
    int row = idx >> 7;
    out[(size_t)row * D + d] = y;        // fp32 output, natural layout
}

__global__ __launch_bounds__(256) void k_final(
    const float* vpre, const void* gamma, const void* beta,
    const float* bnsum, const float* bnsumsq, float* out, int n,
    const int* flag)
{
    if (*flag)
        final_body<float>(vpre, (const float*)gamma, (const float*)beta,
                          bnsum, bnsumsq, out, n);
    else
        final_body<bf16>(vpre, (const bf16*)gamma, (const bf16*)beta,
                         bnsum, bnsumsq, out, n);
}

// ---------------------------------------------------------------- launch
extern "C" void kernel_launch(void* const* d_in, const int* in_sizes, int n_in,
                              void* d_out, int out_size, void* d_ws, size_t ws_size,
                              hipStream_t stream)
{
    const int*  x     = (const int*)d_in[0];
    const int*  ei    = (const int*)d_in[1];
    const void* ew    = d_in[2];
    const void* emb   = d_in[3];
    const void* Wl    = d_in[4];
    const void* bl    = d_in[5];
    const void* Wr    = d_in[6];
    const void* br    = d_in[7];
    const void* att   = d_in[8];
    const void* We    = d_in[9];
    const void* bias  = d_in[10];
    const void* gamma = d_in[11];
    const void* beta  = d_in[12];

    const int n  = in_sizes[0];        // 50000
    const int nE = in_sizes[1] / 2;    // 800000

    // ws layout: xl | xr | vpre | deg | bnsum | bnsumsq | flag | row_ptr | cursor | csr
    float* ws      = (float*)d_ws;
    float* xl      = ws;
    float* xr      = xl + (size_t)n * D;
    float* vpre    = xr + (size_t)n * D;
    int*   deg     = (int*)(vpre + (size_t)n * D);
    float* bnsum   = (float*)(deg + n);
    float* bnsumsq = bnsum + D;
    int*   flag    = (int*)(bnsumsq + D);
    int*   row_ptr = flag + 1;
    int*   cursor  = row_ptr + (n + 1);
    uintptr_t p    = (uintptr_t)(cursor + n);
    p = (p + 7) & ~(uintptr_t)7;
    int2*  csr     = (int2*)p;

    int zcount = n + 2 * D;            // deg + bnsum + bnsumsq
    k_zero_detect<<<(zcount + 255) / 256, 256, 0, stream>>>(
        deg, zcount, (const unsigned short*)emb, flag);

    int nodeBlocks = (n + 7) / 8;
    int histBlocks = (nE + 255) / 256;
    k_node_hist<<<nodeBlocks + histBlocks, 256, 0, stream>>>(
        x, emb, Wl, bl, Wr, br, xl, xr, n, flag, ei, deg, nE, nodeBlocks);

    k_scan<<<1, 1024, 0, stream>>>(deg, row_ptr, cursor, n);

    k_scatter<<<(nE + 255) / 256, 256, 0, stream>>>(ei, cursor, csr, nE);

    k_agg<<<2500, 256, 0, stream>>>(row_ptr, csr, ew, We, att, bias,
                                    xl, xr, vpre, bnsum, bnsumsq, n, flag);

    int totalOut = n * D;
    k_final<<<(totalOut + 255) / 256, 256, 0, stream>>>(vpre, gamma, beta,
                                                        bnsum, bnsumsq,
                                                        (float*)d_out, n, flag);
}